// Round 14
// baseline (215.140 us; speedup 1.0000x reference)
//
#include <hip/hip_runtime.h>
#include <math.h>

#define DIN  128
#define DOUT 64
#define PROWS 64    // rows per proj tile
#define KS   32     // k-slab depth
#define BSH  6      // bucket = dst >> 6 (64 dsts/bucket) -> CSR fits in LDS
#define BMSK 63
#define BCAP 2496   // entries/bucket: mean 2048, sd ~45 -> +10 sigma pad (mult of 64)
#define GSTR 16     // gTail stride: one counter per 64B line (R3-proven atomic spread)

__device__ inline unsigned short f2bf(float f) {          // RNE bf16 round
    unsigned u = __float_as_uint(f);
    u += 0x7fffu + ((u >> 16) & 1u);
    return (unsigned short)(u >> 16);
}
__device__ inline float bflo(unsigned u) { return __uint_as_float(u << 16); }
__device__ inline float bfhi(unsigned u) { return __uint_as_float(u & 0xffff0000u); }

// async 16B global->LDS (no VGPR roundtrip; m97 pattern).  LDS dest must be
// the lane-linear address (wave-uniform base + lane*16).
__device__ inline void gl16(const float* g, float* l) {
    __builtin_amdgcn_global_load_lds(
        (const __attribute__((address_space(1))) unsigned int*)g,
        (__attribute__((address_space(3))) unsigned int*)l, 16, 0, 0);
}

// ---------------------------------------------------------------------------
// K1 fused build_k.  Fill branch: R11 body + gTail 64B-line padding.
// Proj branch R14: k-slab staging via global_load_lds width=16 (deletes the
// load->VGPR->ds_write roundtrip that kept staging on the critical path).
// W-slab is a contiguous 8KB copy (linear).  x-slab uses linear LDS dest +
// pre-swizzled global source (chunk c4 ^= row&7, m173 pattern) and the same
// XOR on reads -> 2-way conflicts only (free).  Arithmetic order per output
// unchanged -> y/z bit-identical to R13.
// ---------------------------------------------------------------------------
__global__ void __launch_bounds__(256) build_k(
    const int* __restrict__ ei, unsigned* __restrict__ gTail,
    int* __restrict__ bucketBuf,
    const float* __restrict__ x, const float* __restrict__ Wl,
    const float* __restrict__ bl, const float* __restrict__ Wr,
    unsigned short* __restrict__ y, float* __restrict__ zout,
    int E, int nFill, int P, int nyb, int n_src, int n_dst, int nB)
{
    __shared__ float s_mem[4096];              // 16KB: x-slab 2048 | W-slab 2048
    const int b = blockIdx.x;
    const int fq = b / P;
    const bool isFill = ((b % P) == 0) && (fq < nFill);

    if (isFill) {
        int* s_i  = (int*)s_mem;     // 3072 ints used (12KB <= 16KB)
        int* lcnt = s_i;             // [1024]
        int* lpos = s_i + 1024;      // [1024]
        int* s_gb = s_i + 2048;      // [1024]
        const int t = threadIdx.x;
        const int myb = (fq * 256 + t) * 8;
        const bool full = (myb + 8 <= E);
        const bool any  = (myb < E);
        int4 sa, sb4, da, db;
        if (full) {
            sa  = *(const int4*)(ei + myb);
            sb4 = *(const int4*)(ei + myb + 4);
            da  = *(const int4*)(ei + E + myb);
            db  = *(const int4*)(ei + E + myb + 4);
        }
        lcnt[t] = 0; lcnt[t + 256] = 0; lcnt[t + 512] = 0; lcnt[t + 768] = 0;
        lpos[t] = 0; lpos[t + 256] = 0; lpos[t + 512] = 0; lpos[t + 768] = 0;
        __syncthreads();
        if (full) {
            atomicAdd(&lcnt[da.x >> BSH], 1); atomicAdd(&lcnt[da.y >> BSH], 1);
            atomicAdd(&lcnt[da.z >> BSH], 1); atomicAdd(&lcnt[da.w >> BSH], 1);
            atomicAdd(&lcnt[db.x >> BSH], 1); atomicAdd(&lcnt[db.y >> BSH], 1);
            atomicAdd(&lcnt[db.z >> BSH], 1); atomicAdd(&lcnt[db.w >> BSH], 1);
        } else if (any) {
            for (int i = myb; i < E && i < myb + 8; ++i)
                atomicAdd(&lcnt[ei[E + i] >> BSH], 1);
        }
        __syncthreads();
        for (int bk = t; bk < nB; bk += 256)
            s_gb[bk] = (int)atomicAdd(&gTail[(size_t)bk * GSTR], (unsigned)lcnt[bk]);
        __syncthreads();
#define PLACE(S, D) { int bk = (D) >> BSH; int p = atomicAdd(&lpos[bk], 1);          \
                      unsigned pos = (unsigned)(s_gb[bk] + p);                        \
                      if (pos < BCAP) bucketBuf[(size_t)bk * BCAP + pos] =            \
                          ((S) << BSH) | ((D) & BMSK); }
        if (full) {
            PLACE(sa.x,  da.x) PLACE(sa.y,  da.y) PLACE(sa.z,  da.z) PLACE(sa.w,  da.w)
            PLACE(sb4.x, db.x) PLACE(sb4.y, db.y) PLACE(sb4.z, db.z) PLACE(sb4.w, db.w)
        } else if (any) {
            for (int i = myb; i < E && i < myb + 8; ++i) {
                int s = ei[i], d = ei[E + i];
                PLACE(s, d)
            }
        }
#undef PLACE
        return;
    }

    // ---- projection: 64 rows x 64 ch per block, gload_lds k-slabs (R14) ----
    const int fillsBefore = (fq + 1 < nFill) ? (fq + 1) : nFill;
    const int pb = b - fillsBefore;            // dense proj index
    const int t  = threadIdx.x;
    const bool isY = (pb < nyb);
    const int rowBase = (isY ? pb : pb - nyb) * PROWS;
    const int nRows = isY ? n_src : n_dst;
    const float* __restrict__ W = isY ? Wl : Wr;

    float* s_xs = s_mem;                       // [64][32] floats, XOR-swizzled chunks
    float* s_ws = s_mem + 2048;                // [KS][DOUT]

    const int cg = t & 15;                     // channel quad: 4cg..4cg+3
    const int rg = t >> 4;                     // row group: rows 4rg..4rg+3
    const int r0 = rg * 4;

    // staging geometry (same for every slab): fi = t + 256j, j=0,1
    const int xrow0 = t >> 3,        xc0 = t & 7;          // j=0
    const int xrow1 = (t + 256) >> 3, xc1 = (t + 256) & 7; // j=1
    const int xs0 = (xc0 ^ (xrow0 & 7)) * 4;   // pre-swizzled src chunk (floats)
    const int xs1 = (xc1 ^ (xrow1 & 7)) * 4;

    // read-side swizzled x bases (floats): row r stores chunk k4 at (k4^(r&7))*4
    const int xb0 = (r0 + 0) * 32, xm0 = (r0 + 0) & 7;
    const int xb1 = (r0 + 1) * 32, xm1 = (r0 + 1) & 7;
    const int xb2 = (r0 + 2) * 32, xm2 = (r0 + 2) & 7;
    const int xb3 = (r0 + 3) * 32, xm3 = (r0 + 3) & 7;

    float4 acc0 = {0.f,0.f,0.f,0.f};
    float4 acc1 = {0.f,0.f,0.f,0.f};
    float4 acc2 = {0.f,0.f,0.f,0.f};
    float4 acc3 = {0.f,0.f,0.f,0.f};

#define ROWFMA(acc, xv)                                                                     \
    acc.x = fmaf(xv.w, w3.x, fmaf(xv.z, w2.x, fmaf(xv.y, w1.x, fmaf(xv.x, w0.x, acc.x)))); \
    acc.y = fmaf(xv.w, w3.y, fmaf(xv.z, w2.y, fmaf(xv.y, w1.y, fmaf(xv.x, w0.y, acc.y)))); \
    acc.z = fmaf(xv.w, w3.z, fmaf(xv.z, w2.z, fmaf(xv.y, w1.z, fmaf(xv.x, w0.z, acc.z)))); \
    acc.w = fmaf(xv.w, w3.w, fmaf(xv.z, w2.w, fmaf(xv.y, w1.w, fmaf(xv.x, w0.w, acc.w))));

    for (int k0 = 0; k0 < DIN; k0 += KS) {
        // stage x slab: 64 rows x 32 k; linear LDS dest, swizzled global src
        {
            const float* xs = x + (size_t)rowBase * DIN + k0;
            if (rowBase + xrow0 < nRows)
                gl16(xs + (size_t)xrow0 * DIN + xs0, s_xs + t * 4);
            if (rowBase + xrow1 < nRows)
                gl16(xs + (size_t)xrow1 * DIN + xs1, s_xs + (t + 256) * 4);
            // stage W slab: contiguous 8KB copy, linear both sides
            const float* ws = W + (size_t)k0 * DOUT;
            gl16(ws + t * 4,         s_ws + t * 4);
            gl16(ws + (t + 256) * 4, s_ws + (t + 256) * 4);
        }
        __syncthreads();                       // drains vmcnt -> LDS ready

        const float* wp = s_ws + cg * 4;
        #pragma unroll 2
        for (int k = 0; k < KS; k += 4) {
            const int k4 = k >> 2;
            float4 w0 = *(const float4*)(wp + (k + 0) * DOUT);
            float4 w1 = *(const float4*)(wp + (k + 1) * DOUT);
            float4 w2 = *(const float4*)(wp + (k + 2) * DOUT);
            float4 w3 = *(const float4*)(wp + (k + 3) * DOUT);
            float4 x0 = *(const float4*)(&s_xs[xb0 + ((k4 ^ xm0) << 2)]);
            float4 x1 = *(const float4*)(&s_xs[xb1 + ((k4 ^ xm1) << 2)]);
            float4 x2 = *(const float4*)(&s_xs[xb2 + ((k4 ^ xm2) << 2)]);
            float4 x3 = *(const float4*)(&s_xs[xb3 + ((k4 ^ xm3) << 2)]);
            ROWFMA(acc0, x0)
            ROWFMA(acc1, x1)
            ROWFMA(acc2, x2)
            ROWFMA(acc3, x3)
        }
        __syncthreads();                       // all reads done before next stage
    }
#undef ROWFMA

    if (isY) {
        float4 av[4] = {acc0, acc1, acc2, acc3};
        #pragma unroll
        for (int r = 0; r < 4; ++r) {
            int row = rowBase + r0 + r;
            if (row < nRows) {
                uint2 pk;
                pk.x = (unsigned)f2bf(av[r].x) | ((unsigned)f2bf(av[r].y) << 16);
                pk.y = (unsigned)f2bf(av[r].z) | ((unsigned)f2bf(av[r].w) << 16);
                *(uint2*)(y + (size_t)row * DOUT + cg * 4) = pk;
            }
        }
    } else {
        const float4 bv = *(const float4*)(bl + cg * 4);
        float4 av[4] = {acc0, acc1, acc2, acc3};
        #pragma unroll
        for (int r = 0; r < 4; ++r) {
            int row = rowBase + r0 + r;
            if (row < nRows) {
                float4 o;
                o.x = av[r].x + bv.x; o.y = av[r].y + bv.y;
                o.z = av[r].z + bv.z; o.w = av[r].w + bv.w;
                *(float4*)(zout + (size_t)row * DOUT + cg * 4) = o;
            }
        }
    }
}

// ---------------------------------------------------------------------------
// K2 bg_k (unchanged from R12 except gTail stride): bucket + gather fused.
// One 512-thread block per bucket (64 dsts, ~2048 entries).  CSR built
// entirely in LDS, then 8 waves gather 64 rows.
// ---------------------------------------------------------------------------
__global__ void __launch_bounds__(512) bg_k(
    const unsigned* __restrict__ gTail, const int* __restrict__ bucketBuf,
    const unsigned short* __restrict__ y,
    float* __restrict__ out, int n_dst)
{
    __shared__ int s_ent[BCAP];
    __shared__ int s_csr[BCAP];
    __shared__ int s_hist[64];
    __shared__ int s_ofs[64];
    __shared__ int s_start[65];
    const int b = blockIdx.x, t = threadIdx.x;
    const int lane = t & 63, wave = t >> 6;

    if (t < 64) s_hist[t] = 0;
    int m = (int)gTail[(size_t)b * GSTR]; if (m > BCAP) m = BCAP;
    __syncthreads();

    const int* bb = bucketBuf + (size_t)b * BCAP;   // 16B aligned (BCAP%4==0)
    const int4* bb4 = (const int4*)bb;
    int4* se4 = (int4*)s_ent;
    const int m4 = m >> 2;
    for (int i4 = t; i4 < m4; i4 += 512) {
        int4 e4 = bb4[i4];
        se4[i4] = e4;
        atomicAdd(&s_hist[e4.x & BMSK], 1);
        atomicAdd(&s_hist[e4.y & BMSK], 1);
        atomicAdd(&s_hist[e4.z & BMSK], 1);
        atomicAdd(&s_hist[e4.w & BMSK], 1);
    }
    for (int i = (m4 << 2) + t; i < m; i += 512) {  // <=3 tail entries
        int e = bb[i];
        s_ent[i] = e;
        atomicAdd(&s_hist[e & BMSK], 1);
    }
    __syncthreads();

    if (wave == 0) {                     // 64-lane inclusive scan of hist
        int h = s_hist[lane];
        int v = h;
        for (int o = 1; o < 64; o <<= 1) {
            int u = __shfl_up(v, o);
            if (lane >= o) v += u;
        }
        s_start[lane + 1] = v;           // row starts (exclusive prefix)
        if (lane == 0) s_start[0] = 0;
        s_ofs[lane] = v - h;             // running placement cursor
    }
    __syncthreads();

    for (int i4 = t; i4 < m4; i4 += 512) {          // exact CSR placement in LDS
        int4 e4 = se4[i4];
        int p0 = atomicAdd(&s_ofs[e4.x & BMSK], 1); s_csr[p0] = e4.x >> BSH;
        int p1 = atomicAdd(&s_ofs[e4.y & BMSK], 1); s_csr[p1] = e4.y >> BSH;
        int p2 = atomicAdd(&s_ofs[e4.z & BMSK], 1); s_csr[p2] = e4.z >> BSH;
        int p3 = atomicAdd(&s_ofs[e4.w & BMSK], 1); s_csr[p3] = e4.w >> BSH;
    }
    for (int i = (m4 << 2) + t; i < m; i += 512) {
        int e = s_ent[i];
        int p = atomicAdd(&s_ofs[e & BMSK], 1);
        s_csr[p] = e >> BSH;
    }
    __syncthreads();

    // ---- gather phase: 8 waves x 8 rows, csr from LDS ----
    const int dbase = b << BSH;
    int nloc = n_dst - dbase; if (nloc > 64) nloc = 64;
    const int g  = lane >> 3;            // edge subgroup 0..7
    const int c8 = lane & 7;             // channel octet: ch 8*c8 .. 8*c8+7
    const uint4* yw = (const uint4*)y;   // one y row = 8 uint4

#define ACC8(al, ah, u)                                              \
    al.x += bflo(u.x); al.y += bfhi(u.x);                            \
    al.z += bflo(u.y); al.w += bfhi(u.y);                            \
    ah.x += bflo(u.z); ah.y += bfhi(u.z);                            \
    ah.z += bflo(u.w); ah.w += bfhi(u.w);

    for (int r = wave; r < nloc; r += 8) {
        const int row = dbase + r;
        const int start = s_start[r];
        const int deg = s_start[r + 1] - start;

        const float4 zv0 = *(const float4*)(out + (size_t)row * DOUT + c8 * 8);
        const float4 zv1 = *(const float4*)(out + (size_t)row * DOUT + c8 * 8 + 4);

        float4 a0l = {0,0,0,0}, a0h = {0,0,0,0};
        float4 a1l = {0,0,0,0}, a1h = {0,0,0,0};
        float4 a2l = {0,0,0,0}, a2h = {0,0,0,0};
        float4 a3l = {0,0,0,0}, a3h = {0,0,0,0};

        for (int co = 0; co < deg; co += 64) {
            int rem = deg - co; if (rem > 64) rem = 64;
            int idx = (lane < rem) ? s_csr[start + co + lane] : 0;
            int i = 0;
            for (; i + 32 <= rem; i += 32) {       // full 32-edge step
                int s0 = __shfl(idx, i + g);
                int s1 = __shfl(idx, i + 8 + g);
                int s2 = __shfl(idx, i + 16 + g);
                int s3 = __shfl(idx, i + 24 + g);
                uint4 u0 = yw[(size_t)s0 * 8 + c8];
                uint4 u1 = yw[(size_t)s1 * 8 + c8];
                uint4 u2 = yw[(size_t)s2 * 8 + c8];
                uint4 u3 = yw[(size_t)s3 * 8 + c8];
                ACC8(a0l, a0h, u0)
                ACC8(a1l, a1h, u1)
                ACC8(a2l, a2h, u2)
                ACC8(a3l, a3h, u3)
            }
            for (; i < rem; i += 8) {              // guarded 8-edge tail
                int e = i + g;
                int s0 = __shfl(idx, e);
                if (e < rem) {
                    uint4 u = yw[(size_t)s0 * 8 + c8];
                    ACC8(a0l, a0h, u)
                }
            }
        }

        float4 sl, sh;
        sl.x = (a0l.x + a1l.x) + (a2l.x + a3l.x);
        sl.y = (a0l.y + a1l.y) + (a2l.y + a3l.y);
        sl.z = (a0l.z + a1l.z) + (a2l.z + a3l.z);
        sl.w = (a0l.w + a1l.w) + (a2l.w + a3l.w);
        sh.x = (a0h.x + a1h.x) + (a2h.x + a3h.x);
        sh.y = (a0h.y + a1h.y) + (a2h.y + a3h.y);
        sh.z = (a0h.z + a1h.z) + (a2h.z + a3h.z);
        sh.w = (a0h.w + a1h.w) + (a2h.w + a3h.w);

        #pragma unroll
        for (int o = 32; o >= 8; o >>= 1) {        // reduce edge subgroups
            sl.x += __shfl_xor(sl.x, o); sl.y += __shfl_xor(sl.y, o);
            sl.z += __shfl_xor(sl.z, o); sl.w += __shfl_xor(sl.w, o);
            sh.x += __shfl_xor(sh.x, o); sh.y += __shfl_xor(sh.y, o);
            sh.z += __shfl_xor(sh.z, o); sh.w += __shfl_xor(sh.w, o);
        }

        const float scale = 1.0f / (float)(deg > 0 ? deg : 1);
        float4 v0, v1;
        v0.x = sl.x * scale + zv0.x; v0.y = sl.y * scale + zv0.y;
        v0.z = sl.z * scale + zv0.z; v0.w = sl.w * scale + zv0.w;
        v1.x = sh.x * scale + zv1.x; v1.y = sh.y * scale + zv1.y;
        v1.z = sh.z * scale + zv1.z; v1.w = sh.w * scale + zv1.w;

        float mx = fmaxf(fmaxf(fmaxf(v0.x, v0.y), fmaxf(v0.z, v0.w)),
                         fmaxf(fmaxf(v1.x, v1.y), fmaxf(v1.z, v1.w)));
        for (int o = 4; o >= 1; o >>= 1) mx = fmaxf(mx, __shfl_xor(mx, o));
        float s = expf(v0.x - mx) + expf(v0.y - mx) + expf(v0.z - mx) + expf(v0.w - mx)
                + expf(v1.x - mx) + expf(v1.y - mx) + expf(v1.z - mx) + expf(v1.w - mx);
        for (int o = 4; o >= 1; o >>= 1) s += __shfl_xor(s, o);
        const float lse = mx + logf(s);

        if (lane < 8) {
            float4 o0, o1;
            o0.x = v0.x - lse; o0.y = v0.y - lse; o0.z = v0.z - lse; o0.w = v0.w - lse;
            o1.x = v1.x - lse; o1.y = v1.y - lse; o1.z = v1.z - lse; o1.w = v1.w - lse;
            *(float4*)(out + (size_t)row * DOUT + c8 * 8)     = o0;
            *(float4*)(out + (size_t)row * DOUT + c8 * 8 + 4) = o1;
        }
    }
#undef ACC8
}

extern "C" void kernel_launch(void* const* d_in, const int* in_sizes, int n_in,
                              void* d_out, int out_size, void* d_ws, size_t ws_size,
                              hipStream_t stream)
{
    const float* x  = (const float*)d_in[0];
    const float* Wl = (const float*)d_in[1];
    const float* bl = (const float*)d_in[2];
    const float* Wr = (const float*)d_in[3];
    const int*   ei = (const int*)d_in[4];

    const int E     = in_sizes[4] / 2;     // 1,600,000
    const int n_src = in_sizes[0] / DIN;   // 100,000
    const int n_dst = out_size / DOUT;     // 50,000
    const int nB    = (n_dst + (1 << BSH) - 1) >> BSH;   // 782

    // ws layout (ints): gTail[nB*GSTR] | buckets[nB*BCAP] | y(bf16)
    unsigned* gTail = (unsigned*)d_ws;
    int* bucketBuf = (int*)d_ws + (size_t)nB * GSTR;
    unsigned short* yb = (unsigned short*)(bucketBuf + (size_t)nB * BCAP);
    // total ~= 0.05 + 7.8 + 12.8 ~= 20.7 MB

    hipMemsetAsync(gTail, 0, (size_t)nB * GSTR * sizeof(unsigned), stream);

    int nFill = (E + 2047) / 2048;         // 782 (8 edges/thread, 256 thr/block)
    int nyb = (n_src + PROWS - 1) / PROWS; // 1563
    int nzb = (n_dst + PROWS - 1) / PROWS; // 782
    int total = nFill + nyb + nzb;         // 3127
    int P = (total + nFill - 1) / nFill;   // 4 -> 1 fill per 4 blocks

    build_k<<<total, 256, 0, stream>>>(
        ei, gTail, bucketBuf, x, Wl, bl, Wr, yb, (float*)d_out,
        E, nFill, P, nyb, n_src, n_dst, nB);

    bg_k<<<nB, 512, 0, stream>>>(gTail, bucketBuf, yb, (float*)d_out, n_dst);
}

// Round 15
// 198.790 us; speedup vs baseline: 1.0822x; 1.0822x over previous
//
#include <hip/hip_runtime.h>
#include <math.h>

#define DIN  128
#define DOUT 64
#define PROWS 64    // rows per proj tile
#define KS   32     // k-slab depth
#define XSP  36     // x-slab pitch floats (32+4): 144B = 16B-mult, rows spread banks
#define BSH  5      // bucket = dst >> 5 (32 dsts/bucket) -> 1564 buckets, 2x bg parallelism (R15)
#define BMSK 31
#define BCAP 1344   // entries/bucket: mean 1024, sd ~32 -> +10 sigma pad (mult of 64)

__device__ inline unsigned short f2bf(float f) {          // RNE bf16 round
    unsigned u = __float_as_uint(f);
    u += 0x7fffu + ((u >> 16) & 1u);
    return (unsigned short)(u >> 16);
}
__device__ inline float bflo(unsigned u) { return __uint_as_float(u << 16); }
__device__ inline float bfhi(unsigned u) { return __uint_as_float(u & 0xffff0000u); }

// ---------------------------------------------------------------------------
// K1 fused build_k.  Fill branch: R11 body widened to 2048 bucket counters.
// Proj branch: EXACT R13 k-slab LDS staging (66us proven; R14's
// global_load_lds conversion regressed 66->78 with WRITE_SIZE +21MB and was
// reverted -- the vmcnt(0) barrier drain beats the ds_write path here).
// Arithmetic order per output unchanged -> y/z bit-identical to R13.
// ---------------------------------------------------------------------------
__global__ void __launch_bounds__(256) build_k(
    const int* __restrict__ ei, unsigned* __restrict__ gTail,
    int* __restrict__ bucketBuf,
    const float* __restrict__ x, const float* __restrict__ Wl,
    const float* __restrict__ bl, const float* __restrict__ Wr,
    unsigned short* __restrict__ y, float* __restrict__ zout,
    int E, int nFill, int P, int nyb, int n_src, int n_dst, int nB)
{
    __shared__ float s_mem[6144];              // 24KB: fill 3x2048 ints | proj 4352 floats
    const int b = blockIdx.x;
    const int fq = b / P;
    const bool isFill = ((b % P) == 0) && (fq < nFill);

    if (isFill) {
        int* s_i  = (int*)s_mem;
        int* lcnt = s_i;             // [2048]
        int* lpos = s_i + 2048;      // [2048]
        int* s_gb = s_i + 4096;      // [2048]
        const int t = threadIdx.x;
        const int myb = (fq * 256 + t) * 8;
        const bool full = (myb + 8 <= E);
        const bool any  = (myb < E);
        int4 sa, sb4, da, db;
        if (full) {
            sa  = *(const int4*)(ei + myb);
            sb4 = *(const int4*)(ei + myb + 4);
            da  = *(const int4*)(ei + E + myb);
            db  = *(const int4*)(ei + E + myb + 4);
        }
        #pragma unroll
        for (int k = 0; k < 8; ++k) { lcnt[t + k * 256] = 0; lpos[t + k * 256] = 0; }
        __syncthreads();
        if (full) {
            atomicAdd(&lcnt[da.x >> BSH], 1); atomicAdd(&lcnt[da.y >> BSH], 1);
            atomicAdd(&lcnt[da.z >> BSH], 1); atomicAdd(&lcnt[da.w >> BSH], 1);
            atomicAdd(&lcnt[db.x >> BSH], 1); atomicAdd(&lcnt[db.y >> BSH], 1);
            atomicAdd(&lcnt[db.z >> BSH], 1); atomicAdd(&lcnt[db.w >> BSH], 1);
        } else if (any) {
            for (int i = myb; i < E && i < myb + 8; ++i)
                atomicAdd(&lcnt[ei[E + i] >> BSH], 1);
        }
        __syncthreads();
        for (int bk = t; bk < nB; bk += 256)
            s_gb[bk] = (int)atomicAdd(&gTail[bk], (unsigned)lcnt[bk]);
        __syncthreads();
#define PLACE(S, D) { int bk = (D) >> BSH; int p = atomicAdd(&lpos[bk], 1);          \
                      unsigned pos = (unsigned)(s_gb[bk] + p);                        \
                      if (pos < BCAP) bucketBuf[(size_t)bk * BCAP + pos] =            \
                          ((S) << BSH) | ((D) & BMSK); }
        if (full) {
            PLACE(sa.x,  da.x) PLACE(sa.y,  da.y) PLACE(sa.z,  da.z) PLACE(sa.w,  da.w)
            PLACE(sb4.x, db.x) PLACE(sb4.y, db.y) PLACE(sb4.z, db.z) PLACE(sb4.w, db.w)
        } else if (any) {
            for (int i = myb; i < E && i < myb + 8; ++i) {
                int s = ei[i], d = ei[E + i];
                PLACE(s, d)
            }
        }
#undef PLACE
        return;
    }

    // ---- projection: 64 rows x 64 ch per block, k-slab staged (R13 body) ----
    const int fillsBefore = (fq + 1 < nFill) ? (fq + 1) : nFill;
    const int pb = b - fillsBefore;            // dense proj index
    const int t  = threadIdx.x;
    const bool isY = (pb < nyb);
    const int rowBase = (isY ? pb : pb - nyb) * PROWS;
    const int nRows = isY ? n_src : n_dst;
    const float* __restrict__ W = isY ? Wl : Wr;

    float* s_xs = s_mem;                       // [64][XSP]
    float* s_ws = s_mem + PROWS * XSP;         // [KS][DOUT]

    const int cg = t & 15;                     // channel quad: 4cg..4cg+3
    const int rg = t >> 4;                     // row group: rows 4rg..4rg+3
    const int r0 = rg * 4;

    float4 acc0 = {0.f,0.f,0.f,0.f};
    float4 acc1 = {0.f,0.f,0.f,0.f};
    float4 acc2 = {0.f,0.f,0.f,0.f};
    float4 acc3 = {0.f,0.f,0.f,0.f};

#define ROWFMA(acc, xv)                                                                     \
    acc.x = fmaf(xv.w, w3.x, fmaf(xv.z, w2.x, fmaf(xv.y, w1.x, fmaf(xv.x, w0.x, acc.x)))); \
    acc.y = fmaf(xv.w, w3.y, fmaf(xv.z, w2.y, fmaf(xv.y, w1.y, fmaf(xv.x, w0.y, acc.y)))); \
    acc.z = fmaf(xv.w, w3.z, fmaf(xv.z, w2.z, fmaf(xv.y, w1.z, fmaf(xv.x, w0.z, acc.z)))); \
    acc.w = fmaf(xv.w, w3.w, fmaf(xv.z, w2.w, fmaf(xv.y, w1.w, fmaf(xv.x, w0.w, acc.w))));

    for (int k0 = 0; k0 < DIN; k0 += KS) {
        // stage x slab: 64 rows x 32 k = 512 float4 (8 lanes x 128B per row)
        {
            const float* xs = x + (size_t)rowBase * DIN + k0;
            #pragma unroll
            for (int j = 0; j < 2; ++j) {
                int fi = t + 256 * j;          // 0..511
                int row = fi >> 3, c4 = fi & 7;
                if (rowBase + row < nRows) {
                    float4 v = *(const float4*)(xs + (size_t)row * DIN + c4 * 4);
                    *(float4*)(&s_xs[row * XSP + c4 * 4]) = v;
                }
            }
            // stage w slab: 32 k x 64 ch = 512 float4 (16 lanes x 256B per k)
            const float* ws = W + (size_t)k0 * DOUT;
            #pragma unroll
            for (int j = 0; j < 2; ++j) {
                int fi = t + 256 * j;
                int row = fi >> 4, c4 = fi & 15;
                float4 v = *(const float4*)(ws + row * DOUT + c4 * 4);
                *(float4*)(&s_ws[row * DOUT + c4 * 4]) = v;
            }
        }
        __syncthreads();

        const float* wp = s_ws + cg * 4;
        #pragma unroll 2
        for (int k = 0; k < KS; k += 4) {
            float4 w0 = *(const float4*)(wp + (k + 0) * DOUT);
            float4 w1 = *(const float4*)(wp + (k + 1) * DOUT);
            float4 w2 = *(const float4*)(wp + (k + 2) * DOUT);
            float4 w3 = *(const float4*)(wp + (k + 3) * DOUT);
            float4 x0 = *(const float4*)(&s_xs[(r0 + 0) * XSP + k]);
            float4 x1 = *(const float4*)(&s_xs[(r0 + 1) * XSP + k]);
            float4 x2 = *(const float4*)(&s_xs[(r0 + 2) * XSP + k]);
            float4 x3 = *(const float4*)(&s_xs[(r0 + 3) * XSP + k]);
            ROWFMA(acc0, x0)
            ROWFMA(acc1, x1)
            ROWFMA(acc2, x2)
            ROWFMA(acc3, x3)
        }
        __syncthreads();
    }
#undef ROWFMA

    if (isY) {
        float4 av[4] = {acc0, acc1, acc2, acc3};
        #pragma unroll
        for (int r = 0; r < 4; ++r) {
            int row = rowBase + r0 + r;
            if (row < nRows) {
                uint2 pk;
                pk.x = (unsigned)f2bf(av[r].x) | ((unsigned)f2bf(av[r].y) << 16);
                pk.y = (unsigned)f2bf(av[r].z) | ((unsigned)f2bf(av[r].w) << 16);
                *(uint2*)(y + (size_t)row * DOUT + cg * 4) = pk;
            }
        }
    } else {
        const float4 bv = *(const float4*)(bl + cg * 4);
        float4 av[4] = {acc0, acc1, acc2, acc3};
        #pragma unroll
        for (int r = 0; r < 4; ++r) {
            int row = rowBase + r0 + r;
            if (row < nRows) {
                float4 o;
                o.x = av[r].x + bv.x; o.y = av[r].y + bv.y;
                o.z = av[r].z + bv.z; o.w = av[r].w + bv.w;
                *(float4*)(zout + (size_t)row * DOUT + cg * 4) = o;
            }
        }
    }
}

// ---------------------------------------------------------------------------
// K2 bg_k (R15: BSH=5): bucket + gather fused, one 512-thread block per
// bucket (32 dsts, ~1024 entries).  Halves per-block serial phase-1 chain
// and phase-2 gather vs R12's 64-dst buckets; 2x block parallelism (1564
// blocks, ~6/CU).  CSR built entirely in LDS; 8 waves x 4 rows gather.
// ---------------------------------------------------------------------------
__global__ void __launch_bounds__(512) bg_k(
    const unsigned* __restrict__ gTail, const int* __restrict__ bucketBuf,
    const unsigned short* __restrict__ y,
    float* __restrict__ out, int n_dst)
{
    __shared__ int s_ent[BCAP];
    __shared__ int s_csr[BCAP];
    __shared__ int s_hist[32];
    __shared__ int s_ofs[32];
    __shared__ int s_start[33];
    const int b = blockIdx.x, t = threadIdx.x;
    const int lane = t & 63, wave = t >> 6;

    if (t < 32) s_hist[t] = 0;
    int m = (int)gTail[b]; if (m > BCAP) m = BCAP;
    __syncthreads();

    const int* bb = bucketBuf + (size_t)b * BCAP;   // 16B aligned (BCAP%4==0)
    const int4* bb4 = (const int4*)bb;
    int4* se4 = (int4*)s_ent;
    const int m4 = m >> 2;
    for (int i4 = t; i4 < m4; i4 += 512) {
        int4 e4 = bb4[i4];
        se4[i4] = e4;
        atomicAdd(&s_hist[e4.x & BMSK], 1);
        atomicAdd(&s_hist[e4.y & BMSK], 1);
        atomicAdd(&s_hist[e4.z & BMSK], 1);
        atomicAdd(&s_hist[e4.w & BMSK], 1);
    }
    for (int i = (m4 << 2) + t; i < m; i += 512) {  // <=3 tail entries
        int e = bb[i];
        s_ent[i] = e;
        atomicAdd(&s_hist[e & BMSK], 1);
    }
    __syncthreads();

    if (wave == 0) {                     // 32-lane inclusive scan of hist
        int h = (lane < 32) ? s_hist[lane] : 0;
        int v = h;
        for (int o = 1; o < 32; o <<= 1) {
            int u = __shfl_up(v, o);
            if (lane >= o) v += u;
        }
        if (lane < 32) {
            s_start[lane + 1] = v;       // row starts (exclusive prefix)
            if (lane == 0) s_start[0] = 0;
            s_ofs[lane] = v - h;         // running placement cursor
        }
    }
    __syncthreads();

    for (int i4 = t; i4 < m4; i4 += 512) {          // exact CSR placement in LDS
        int4 e4 = se4[i4];
        int p0 = atomicAdd(&s_ofs[e4.x & BMSK], 1); s_csr[p0] = e4.x >> BSH;
        int p1 = atomicAdd(&s_ofs[e4.y & BMSK], 1); s_csr[p1] = e4.y >> BSH;
        int p2 = atomicAdd(&s_ofs[e4.z & BMSK], 1); s_csr[p2] = e4.z >> BSH;
        int p3 = atomicAdd(&s_ofs[e4.w & BMSK], 1); s_csr[p3] = e4.w >> BSH;
    }
    for (int i = (m4 << 2) + t; i < m; i += 512) {
        int e = s_ent[i];
        int p = atomicAdd(&s_ofs[e & BMSK], 1);
        s_csr[p] = e >> BSH;
    }
    __syncthreads();

    // ---- gather phase: 8 waves x 4 rows, csr from LDS ----
    const int dbase = b << BSH;
    int nloc = n_dst - dbase; if (nloc > 32) nloc = 32;
    const int g  = lane >> 3;            // edge subgroup 0..7
    const int c8 = lane & 7;             // channel octet: ch 8*c8 .. 8*c8+7
    const uint4* yw = (const uint4*)y;   // one y row = 8 uint4

#define ACC8(al, ah, u)                                              \
    al.x += bflo(u.x); al.y += bfhi(u.x);                            \
    al.z += bflo(u.y); al.w += bfhi(u.y);                            \
    ah.x += bflo(u.z); ah.y += bfhi(u.z);                            \
    ah.z += bflo(u.w); ah.w += bfhi(u.w);

    for (int r = wave; r < nloc; r += 8) {
        const int row = dbase + r;
        const int start = s_start[r];
        const int deg = s_start[r + 1] - start;

        const float4 zv0 = *(const float4*)(out + (size_t)row * DOUT + c8 * 8);
        const float4 zv1 = *(const float4*)(out + (size_t)row * DOUT + c8 * 8 + 4);

        float4 a0l = {0,0,0,0}, a0h = {0,0,0,0};
        float4 a1l = {0,0,0,0}, a1h = {0,0,0,0};
        float4 a2l = {0,0,0,0}, a2h = {0,0,0,0};
        float4 a3l = {0,0,0,0}, a3h = {0,0,0,0};

        for (int co = 0; co < deg; co += 64) {
            int rem = deg - co; if (rem > 64) rem = 64;
            int idx = (lane < rem) ? s_csr[start + co + lane] : 0;
            int i = 0;
            for (; i + 32 <= rem; i += 32) {       // full 32-edge step
                int s0 = __shfl(idx, i + g);
                int s1 = __shfl(idx, i + 8 + g);
                int s2 = __shfl(idx, i + 16 + g);
                int s3 = __shfl(idx, i + 24 + g);
                uint4 u0 = yw[(size_t)s0 * 8 + c8];
                uint4 u1 = yw[(size_t)s1 * 8 + c8];
                uint4 u2 = yw[(size_t)s2 * 8 + c8];
                uint4 u3 = yw[(size_t)s3 * 8 + c8];
                ACC8(a0l, a0h, u0)
                ACC8(a1l, a1h, u1)
                ACC8(a2l, a2h, u2)
                ACC8(a3l, a3h, u3)
            }
            for (; i < rem; i += 8) {              // guarded 8-edge tail
                int e = i + g;
                int s0 = __shfl(idx, e);
                if (e < rem) {
                    uint4 u = yw[(size_t)s0 * 8 + c8];
                    ACC8(a0l, a0h, u)
                }
            }
        }

        float4 sl, sh;
        sl.x = (a0l.x + a1l.x) + (a2l.x + a3l.x);
        sl.y = (a0l.y + a1l.y) + (a2l.y + a3l.y);
        sl.z = (a0l.z + a1l.z) + (a2l.z + a3l.z);
        sl.w = (a0l.w + a1l.w) + (a2l.w + a3l.w);
        sh.x = (a0h.x + a1h.x) + (a2h.x + a3h.x);
        sh.y = (a0h.y + a1h.y) + (a2h.y + a3h.y);
        sh.z = (a0h.z + a1h.z) + (a2h.z + a3h.z);
        sh.w = (a0h.w + a1h.w) + (a2h.w + a3h.w);

        #pragma unroll
        for (int o = 32; o >= 8; o >>= 1) {        // reduce edge subgroups
            sl.x += __shfl_xor(sl.x, o); sl.y += __shfl_xor(sl.y, o);
            sl.z += __shfl_xor(sl.z, o); sl.w += __shfl_xor(sl.w, o);
            sh.x += __shfl_xor(sh.x, o); sh.y += __shfl_xor(sh.y, o);
            sh.z += __shfl_xor(sh.z, o); sh.w += __shfl_xor(sh.w, o);
        }

        const float scale = 1.0f / (float)(deg > 0 ? deg : 1);
        float4 v0, v1;
        v0.x = sl.x * scale + zv0.x; v0.y = sl.y * scale + zv0.y;
        v0.z = sl.z * scale + zv0.z; v0.w = sl.w * scale + zv0.w;
        v1.x = sh.x * scale + zv1.x; v1.y = sh.y * scale + zv1.y;
        v1.z = sh.z * scale + zv1.z; v1.w = sh.w * scale + zv1.w;

        float mx = fmaxf(fmaxf(fmaxf(v0.x, v0.y), fmaxf(v0.z, v0.w)),
                         fmaxf(fmaxf(v1.x, v1.y), fmaxf(v1.z, v1.w)));
        for (int o = 4; o >= 1; o >>= 1) mx = fmaxf(mx, __shfl_xor(mx, o));
        float s = expf(v0.x - mx) + expf(v0.y - mx) + expf(v0.z - mx) + expf(v0.w - mx)
                + expf(v1.x - mx) + expf(v1.y - mx) + expf(v1.z - mx) + expf(v1.w - mx);
        for (int o = 4; o >= 1; o >>= 1) s += __shfl_xor(s, o);
        const float lse = mx + logf(s);

        if (lane < 8) {
            float4 o0, o1;
            o0.x = v0.x - lse; o0.y = v0.y - lse; o0.z = v0.z - lse; o0.w = v0.w - lse;
            o1.x = v1.x - lse; o1.y = v1.y - lse; o1.z = v1.z - lse; o1.w = v1.w - lse;
            *(float4*)(out + (size_t)row * DOUT + c8 * 8)     = o0;
            *(float4*)(out + (size_t)row * DOUT + c8 * 8 + 4) = o1;
        }
    }
#undef ACC8
}

extern "C" void kernel_launch(void* const* d_in, const int* in_sizes, int n_in,
                              void* d_out, int out_size, void* d_ws, size_t ws_size,
                              hipStream_t stream)
{
    const float* x  = (const float*)d_in[0];
    const float* Wl = (const float*)d_in[1];
    const float* bl = (const float*)d_in[2];
    const float* Wr = (const float*)d_in[3];
    const int*   ei = (const int*)d_in[4];

    const int E     = in_sizes[4] / 2;     // 1,600,000
    const int n_src = in_sizes[0] / DIN;   // 100,000
    const int n_dst = out_size / DOUT;     // 50,000
    const int nB    = (n_dst + (1 << BSH) - 1) >> BSH;   // 1563 -> 1563 buckets

    // ws layout (ints): gTail[2048] | buckets[nB*BCAP] | y(bf16)
    unsigned* gTail = (unsigned*)d_ws;
    int* bucketBuf = (int*)d_ws + 2048;
    unsigned short* yb = (unsigned short*)(bucketBuf + (size_t)nB * BCAP);
    // total ~= 0.008 + 8.4 + 12.8 ~= 21.2 MB

    hipMemsetAsync(gTail, 0, 2048 * sizeof(unsigned), stream);

    int nFill = (E + 2047) / 2048;         // 782 (8 edges/thread, 256 thr/block)
    int nyb = (n_src + PROWS - 1) / PROWS; // 1563
    int nzb = (n_dst + PROWS - 1) / PROWS; // 782
    int total = nFill + nyb + nzb;         // 3127
    int P = (total + nFill - 1) / nFill;   // 4 -> 1 fill per 4 blocks

    build_k<<<total, 256, 0, stream>>>(
        ei, gTail, bucketBuf, x, Wl, bl, Wr, yb, (float*)d_out,
        E, nFill, P, nyb, n_src, n_dst, nB);

    bg_k<<<nB, 512, 0, stream>>>(gTail, bucketBuf, yb, (float*)d_out, n_dst);
}